// Round 1
// baseline (4682.861 us; speedup 1.0000x reference)
//
#include <hip/hip_runtime.h>

typedef __attribute__((ext_vector_type(8))) short short8;
typedef __attribute__((ext_vector_type(4))) float floatx4;

#define DEVI __device__ __forceinline__

// ---------------- level constants ----------------
constexpr int LC[6]   = {512, 1024, 512, 256, 256, 256};   // in channels
constexpr int LS[6]   = {38, 19, 10, 5, 3, 1};             // spatial
constexpr int LA[6]   = {4, 6, 6, 6, 4, 4};                // anchors
constexpr int LROW[6] = {0, 5776, 7942, 8542, 8692, 8728}; // row offsets into 8732
constexpr long FOFF[6] = {0, 23658496, 35487744, 37126144, 37330944, 37404672}; // featT elem offsets
constexpr long WCBASE  = 37412864;                                              // Wc elem base
constexpr long WOFF[6] = {0, 1751040, 7004160, 9630720, 10944000, 11819520};    // Wc per-level offsets
constexpr int  GOFF[7] = {0, 218880, 875520, 1203840, 1368000, 1477440, 1586880}; // groups of 8
constexpr long CLSOFF  = 1117696;            // 32*8732*4
constexpr size_t WS_NEEDED = (size_t)(37412864 + 12695040) * 2;

DEVI short f2bf(float f) {
    union { float f; unsigned u; } x; x.f = f;
    unsigned u = x.u + 0x7fffu + ((x.u >> 16) & 1u);   // RNE
    return (short)(u >> 16);
}

DEVI short8 zero8() {
    short8 z;
#pragma unroll
    for (int q = 0; q < 8; ++q) z[q] = 0;
    return z;
}

// ---------------- transpose feat [n,c,pix] f32 -> [n,pix,c] bf16 ----------------
template<int L>
__global__ void transpose_feat(const float* __restrict__ feat, short* __restrict__ ft) {
    constexpr int C = LC[L], S = LS[L], HW = S * S;
    const int n  = blockIdx.z;
    const int p0 = blockIdx.x * 64;
    const int c0 = blockIdx.y * 64;
    __shared__ float tile[64][65];
    const int t = threadIdx.x;
    const float* fb = feat + ((size_t)n * C + c0) * HW;
#pragma unroll
    for (int e = 0; e < 16; ++e) {
        int idx = e * 256 + t;
        int p = idx & 63, cc = idx >> 6;
        int pix = p0 + p;
        tile[cc][p] = (pix < HW) ? fb[(size_t)cc * HW + pix] : 0.f;
    }
    __syncthreads();
    short* ob = ft + ((size_t)n * HW) * C + c0;
#pragma unroll
    for (int e = 0; e < 16; ++e) {
        int idx = e * 256 + t;
        int cc = idx & 63, p = idx >> 6;
        int pix = p0 + p;
        if (pix < HW) ob[(size_t)pix * C + cc] = f2bf(tile[cc][p]);
    }
}

// ---------------- reorder weights: combined [o][k=r*C+c] bf16 ----------------
struct WPtrs { const float* cw[6]; const float* rw[6]; };

__global__ void reorder_weights(WPtrs p, short* __restrict__ wc) {
    int g = blockIdx.x * 256 + threadIdx.x;
    if (g >= GOFF[6]) return;
    int L = 0;
#pragma unroll
    for (int q = 1; q < 6; ++q) if (g >= GOFF[q]) L = q;
    int e = g - GOFF[L];
    const int C = LC[L], A = LA[L];
    const unsigned K8 = (unsigned)(9 * C) >> 3, C8 = (unsigned)C >> 3;
    unsigned o    = (unsigned)e / K8;
    unsigned remk = (unsigned)e - o * K8;
    unsigned r    = remk / C8;
    unsigned c    = (remk - r * C8) << 3;
    int A4 = A << 2;
    const float* src = ((int)o < A4) ? (p.rw[L] + (size_t)o * 9 * C)
                                     : (p.cw[L] + (size_t)(o - A4) * 9 * C);
    short8 v;
#pragma unroll
    for (int j = 0; j < 8; ++j) v[j] = f2bf(src[(size_t)(c + j) * 9 + r]);
    *(short8*)(wc + (size_t)WOFF[L] + (size_t)o * (9 * C) + (size_t)r * C + c) = v;
}

// ---------------- implicit-GEMM conv, 128x128x32 tile, 16x16x32 bf16 MFMA ----------------
template<int L>
__global__ __launch_bounds__(256, 2)
void gemm_level(const short* __restrict__ ft, const short* __restrict__ wc,
                const float* __restrict__ cls_b, const float* __restrict__ reg_b,
                float* __restrict__ out)
{
    constexpr int C = LC[L], S = LS[L], A = LA[L];
    constexpr int HW = S * S, M = 32 * HW, K = 9 * C, O = 95 * A;
    constexpr int ROWOFF = LROW[L], A4 = 4 * A;

    __shared__ short As[128][40];
    __shared__ short Bs[128][40];

    const int t  = threadIdx.x;
    const int m0 = blockIdx.x * 128;
    const int n0 = blockIdx.y * 128;

    const int kg = t & 3;          // 16B chunk within BK=32
    const int i0 = t >> 2;         // 0..63 (row; +64 for second item)

    int nn[2], py[2], px[2]; bool mv[2];
#pragma unroll
    for (int e = 0; e < 2; ++e) {
        int m = m0 + i0 + e * 64;
        mv[e] = m < M;
        int mm = mv[e] ? m : 0;
        nn[e] = mm / HW;
        int rem = mm - nn[e] * HW;
        py[e] = rem / S;
        px[e] = rem - py[e] * S;
    }
    bool ov[2]; const short* bbase[2];
#pragma unroll
    for (int e = 0; e < 2; ++e) {
        int orow = n0 + i0 + e * 64;
        ov[e] = orow < O;
        int oc = ov[e] ? orow : (O - 1);
        bbase[e] = wc + (size_t)oc * K + kg * 8;
    }

    const int lane = t & 63;
    const int wid  = t >> 6;
    const int wm   = (wid & 1) * 64;
    const int wn   = (wid >> 1) * 64;
    const int lcol  = lane & 15;
    const int lquad = lane >> 4;

    floatx4 acc[4][4];
#pragma unroll
    for (int i = 0; i < 4; ++i)
#pragma unroll
        for (int j = 0; j < 4; ++j)
#pragma unroll
            for (int q = 0; q < 4; ++q) acc[i][j][q] = 0.f;

#pragma unroll 1
    for (int r = 0; r < 9; ++r) {
        const int kh = r / 3 - 1, kw = r - (r / 3) * 3 - 1;
        const short* ap[2]; bool av[2];
#pragma unroll
        for (int e = 0; e < 2; ++e) {
            int y = py[e] + kh, x = px[e] + kw;
            av[e] = mv[e] && ((unsigned)y < (unsigned)S) && ((unsigned)x < (unsigned)S);
            ap[e] = ft + ((size_t)(nn[e] * HW + y * S + x)) * C + kg * 8;
        }
        const short* bp0 = bbase[0] + r * C;
        const short* bp1 = bbase[1] + r * C;
#pragma unroll 1
        for (int c0 = 0; c0 < C; c0 += 32) {
            short8 a0 = zero8(), a1 = zero8(), b0 = zero8(), b1 = zero8();
            if (av[0]) a0 = *(const short8*)(ap[0] + c0);
            if (av[1]) a1 = *(const short8*)(ap[1] + c0);
            if (ov[0]) b0 = *(const short8*)(bp0 + c0);
            if (ov[1]) b1 = *(const short8*)(bp1 + c0);
            __syncthreads();
            *(short8*)&As[i0     ][kg * 8] = a0;
            *(short8*)&As[i0 + 64][kg * 8] = a1;
            *(short8*)&Bs[i0     ][kg * 8] = b0;
            *(short8*)&Bs[i0 + 64][kg * 8] = b1;
            __syncthreads();
            short8 af[4], bfr[4];
#pragma unroll
            for (int f = 0; f < 4; ++f) {
                af[f]  = *(const short8*)&As[wm + f * 16 + lcol][lquad * 8];
                bfr[f] = *(const short8*)&Bs[wn + f * 16 + lcol][lquad * 8];
            }
#pragma unroll
            for (int i = 0; i < 4; ++i)
#pragma unroll
                for (int j = 0; j < 4; ++j)
                    acc[i][j] = __builtin_amdgcn_mfma_f32_16x16x32_bf16(af[i], bfr[j], acc[i][j], 0, 0, 0);
        }
    }

    // ---------------- epilogue: scatter into [n, 8732, {4|91}] ----------------
    float* const bbox = out;
    float* const cls  = out + CLSOFF;
    int rn[16], rbase[16]; bool rv[16];
#pragma unroll
    for (int fm = 0; fm < 4; ++fm)
#pragma unroll
        for (int rg = 0; rg < 4; ++rg) {
            int idx = fm * 4 + rg;
            int mr = m0 + wm + fm * 16 + lquad * 4 + rg;
            rv[idx] = mr < M;
            int mm = rv[idx] ? mr : 0;
            int n = mm / HW;
            int rem = mm - n * HW;
            rn[idx] = n;
            rbase[idx] = ROWOFF + rem * A;
        }
#pragma unroll 1
    for (int fn = 0; fn < 4; ++fn) {
        int o = n0 + wn + fn * 16 + lcol;
        if (o >= O) continue;
        if (o < A4) {
            int a = o >> 2, cc = o & 3;
            float bias = reg_b[o];
#pragma unroll
            for (int fm = 0; fm < 4; ++fm)
#pragma unroll
                for (int rg = 0; rg < 4; ++rg) {
                    int idx = fm * 4 + rg;
                    if (!rv[idx]) continue;
                    bbox[((size_t)rn[idx] * 8732 + rbase[idx] + a) * 4 + cc] = acc[fm][fn][rg] + bias;
                }
        } else {
            int oc = o - A4;
            int a = oc / 91, cc = oc - a * 91;
            float bias = cls_b[oc];
#pragma unroll
            for (int fm = 0; fm < 4; ++fm)
#pragma unroll
                for (int rg = 0; rg < 4; ++rg) {
                    int idx = fm * 4 + rg;
                    if (!rv[idx]) continue;
                    cls[((size_t)rn[idx] * 8732 + rbase[idx] + a) * 91 + cc] = acc[fm][fn][rg] + bias;
                }
        }
    }
}

// ---------------- naive fallback (only if ws too small) ----------------
template<int L>
__global__ void naive_conv(const float* __restrict__ feat,
                           const float* __restrict__ cw, const float* __restrict__ cb,
                           const float* __restrict__ rw, const float* __restrict__ rb,
                           float* __restrict__ out)
{
    constexpr int C = LC[L], S = LS[L], A = LA[L];
    constexpr int HW = S * S, M = 32 * HW, A4 = 4 * A, ROWOFF = LROW[L];
    int m = blockIdx.x * 256 + threadIdx.x;
    if (m >= M) return;
    int o = blockIdx.y;
    int n = m / HW, rem = m - n * HW, h = rem / S, w = rem - (rem / S) * S;
    bool isreg = o < A4;
    const float* wr = isreg ? (rw + (size_t)o * C * 9) : (cw + (size_t)(o - A4) * C * 9);
    float sum = isreg ? rb[o] : cb[o - A4];
    const float* fb = feat + (size_t)n * C * HW;
    for (int c = 0; c < C; ++c) {
#pragma unroll
        for (int r = 0; r < 9; ++r) {
            int y = h + r / 3 - 1, x = w + r % 3 - 1;
            if ((unsigned)y < (unsigned)S && (unsigned)x < (unsigned)S)
                sum += wr[c * 9 + r] * fb[(size_t)c * HW + y * S + x];
        }
    }
    int rowidx = ROWOFF + rem * A;
    if (isreg) out[((size_t)n * 8732 + rowidx + (o >> 2)) * 4 + (o & 3)] = sum;
    else {
        int oc = o - A4;
        int a = oc / 91;
        (out + CLSOFF)[((size_t)n * 8732 + rowidx + a) * 91 + (oc - a * 91)] = sum;
    }
}

// ---------------- host ----------------
extern "C" void kernel_launch(void* const* d_in, const int* in_sizes, int n_in,
                              void* d_out, int out_size, void* d_ws, size_t ws_size,
                              hipStream_t stream)
{
    const float *feat[6], *cw[6], *cb[6], *rw[6], *rb[6];
    for (int i = 0; i < 6; ++i) {
        feat[i] = (const float*)d_in[5 * i + 0];
        cw[i]   = (const float*)d_in[5 * i + 1];
        cb[i]   = (const float*)d_in[5 * i + 2];
        rw[i]   = (const float*)d_in[5 * i + 3];
        rb[i]   = (const float*)d_in[5 * i + 4];
    }
    float* out = (float*)d_out;

    if (ws_size >= WS_NEEDED) {
        short* ws  = (short*)d_ws;
        short* wcp = ws + WCBASE;
        transpose_feat<0><<<dim3(23, 8, 32), 256, 0, stream>>>(feat[0], ws + FOFF[0]);
        transpose_feat<1><<<dim3(6, 16, 32), 256, 0, stream>>>(feat[1], ws + FOFF[1]);
        transpose_feat<2><<<dim3(2, 8, 32), 256, 0, stream>>>(feat[2], ws + FOFF[2]);
        transpose_feat<3><<<dim3(1, 4, 32), 256, 0, stream>>>(feat[3], ws + FOFF[3]);
        transpose_feat<4><<<dim3(1, 4, 32), 256, 0, stream>>>(feat[4], ws + FOFF[4]);
        transpose_feat<5><<<dim3(1, 4, 32), 256, 0, stream>>>(feat[5], ws + FOFF[5]);
        WPtrs wp;
        for (int i = 0; i < 6; ++i) { wp.cw[i] = cw[i]; wp.rw[i] = rw[i]; }
        reorder_weights<<<6200, 256, 0, stream>>>(wp, wcp);
        gemm_level<0><<<dim3(361, 3), 256, 0, stream>>>(ws + FOFF[0], wcp + WOFF[0], cb[0], rb[0], out);
        gemm_level<1><<<dim3(91, 5),  256, 0, stream>>>(ws + FOFF[1], wcp + WOFF[1], cb[1], rb[1], out);
        gemm_level<2><<<dim3(25, 5),  256, 0, stream>>>(ws + FOFF[2], wcp + WOFF[2], cb[2], rb[2], out);
        gemm_level<3><<<dim3(7, 5),   256, 0, stream>>>(ws + FOFF[3], wcp + WOFF[3], cb[3], rb[3], out);
        gemm_level<4><<<dim3(3, 3),   256, 0, stream>>>(ws + FOFF[4], wcp + WOFF[4], cb[4], rb[4], out);
        gemm_level<5><<<dim3(1, 3),   256, 0, stream>>>(ws + FOFF[5], wcp + WOFF[5], cb[5], rb[5], out);
    } else {
        naive_conv<0><<<dim3(181, 380), 256, 0, stream>>>(feat[0], cw[0], cb[0], rw[0], rb[0], out);
        naive_conv<1><<<dim3(46, 570),  256, 0, stream>>>(feat[1], cw[1], cb[1], rw[1], rb[1], out);
        naive_conv<2><<<dim3(13, 570),  256, 0, stream>>>(feat[2], cw[2], cb[2], rw[2], rb[2], out);
        naive_conv<3><<<dim3(4, 570),   256, 0, stream>>>(feat[3], cw[3], cb[3], rw[3], rb[3], out);
        naive_conv<4><<<dim3(2, 380),   256, 0, stream>>>(feat[4], cw[4], cb[4], rw[4], rb[4], out);
        naive_conv<5><<<dim3(1, 380),   256, 0, stream>>>(feat[5], cw[5], cb[5], rw[5], rb[5], out);
    }
}

// Round 2
// 4614.650 us; speedup vs baseline: 1.0148x; 1.0148x over previous
//
#include <hip/hip_runtime.h>

typedef __attribute__((ext_vector_type(8))) short short8;
typedef __attribute__((ext_vector_type(4))) float floatx4;

#define DEVI __device__ __forceinline__

// direct global->LDS, 16B per lane; LDS dest = wave-uniform base + lane*16
#define GLL(g, l) __builtin_amdgcn_global_load_lds(                      \
    (const __attribute__((address_space(1))) void*)(g),                  \
    (__attribute__((address_space(3))) void*)(l), 16, 0, 0)

// ---------------- level constants ----------------
constexpr int LC[6]   = {512, 1024, 512, 256, 256, 256};   // in channels
constexpr int LS[6]   = {38, 19, 10, 5, 3, 1};             // spatial
constexpr int LA[6]   = {4, 6, 6, 6, 4, 4};                // anchors
constexpr int LROW[6] = {0, 5776, 7942, 8542, 8692, 8728}; // row offsets into 8732
constexpr long FOFF[6] = {0, 23658496, 35487744, 37126144, 37330944, 37404672}; // featT elem offsets
constexpr long WCBASE  = 37412864;                                              // Wc elem base
constexpr long WOFF[6] = {0, 1751040, 7004160, 9630720, 10944000, 11819520};    // Wc per-level offsets
constexpr int  GOFF[7] = {0, 218880, 875520, 1203840, 1368000, 1477440, 1586880}; // groups of 8
constexpr long ZOFF    = 50107904;   // zero-sentinel page (elems)
constexpr int  ZSIZE   = 1088;
constexpr long CLSOFF  = 1117696;    // 32*8732*4
constexpr size_t WS_NEEDED = (size_t)(ZOFF + ZSIZE) * 2;

DEVI short f2bf(float f) {
    union { float f; unsigned u; } x; x.f = f;
    unsigned u = x.u + 0x7fffu + ((x.u >> 16) & 1u);   // RNE
    return (short)(u >> 16);
}

// ---------------- transpose feat [n,c,pix] f32 -> [n,pix,c] bf16 ----------------
template<int L>
__global__ void transpose_feat(const float* __restrict__ feat, short* __restrict__ ft) {
    constexpr int C = LC[L], S = LS[L], HW = S * S;
    const int n  = blockIdx.z;
    const int p0 = blockIdx.x * 64;
    const int c0 = blockIdx.y * 64;
    __shared__ float tile[64][65];
    const int t = threadIdx.x;
    const float* fb = feat + ((size_t)n * C + c0) * HW;
#pragma unroll
    for (int e = 0; e < 16; ++e) {
        int idx = e * 256 + t;
        int p = idx & 63, cc = idx >> 6;
        int pix = p0 + p;
        tile[cc][p] = (pix < HW) ? fb[(size_t)cc * HW + pix] : 0.f;
    }
    __syncthreads();
    short* ob = ft + ((size_t)n * HW) * C + c0;
#pragma unroll
    for (int e = 0; e < 16; ++e) {
        int idx = e * 256 + t;
        int cc = idx & 63, p = idx >> 6;
        int pix = p0 + p;
        if (pix < HW) ob[(size_t)pix * C + cc] = f2bf(tile[cc][p]);
    }
}

// ---------------- reorder weights: combined [o][k=r*C+c] bf16; also zero-fill sentinel ----------------
struct WPtrs { const float* cw[6]; const float* rw[6]; };

__global__ void reorder_weights(WPtrs p, short* __restrict__ wc, short* __restrict__ zb) {
    int g = blockIdx.x * 256 + threadIdx.x;
    if (g >= GOFF[6]) {
        if (blockIdx.x == 6199 && threadIdx.x < ZSIZE / 8) {
            short8 z;
#pragma unroll
            for (int q = 0; q < 8; ++q) z[q] = 0;
            *(short8*)(zb + threadIdx.x * 8) = z;
        }
        return;
    }
    int L = 0;
#pragma unroll
    for (int q = 1; q < 6; ++q) if (g >= GOFF[q]) L = q;
    int e = g - GOFF[L];
    const int C = LC[L], A = LA[L];
    const unsigned K8 = (unsigned)(9 * C) >> 3, C8 = (unsigned)C >> 3;
    unsigned o    = (unsigned)e / K8;
    unsigned remk = (unsigned)e - o * K8;
    unsigned r    = remk / C8;
    unsigned c    = (remk - r * C8) << 3;
    int A4 = A << 2;
    const float* src = ((int)o < A4) ? (p.rw[L] + (size_t)o * 9 * C)
                                     : (p.cw[L] + (size_t)(o - A4) * 9 * C);
    short8 v;
#pragma unroll
    for (int j = 0; j < 8; ++j) v[j] = f2bf(src[(size_t)(c + j) * 9 + r]);
    *(short8*)(wc + (size_t)WOFF[L] + (size_t)o * (9 * C) + (size_t)r * C + c) = v;
}

// ---------------- implicit-GEMM conv, m97 structure: global_load_lds, 128x128x32 ----------------
template<int L>
__global__ __launch_bounds__(256)
void gemm_level(const short* __restrict__ ft, const short* __restrict__ wc,
                const short* __restrict__ zb,
                const float* __restrict__ cls_b, const float* __restrict__ reg_b,
                float* __restrict__ out)
{
    constexpr int C = LC[L], S = LS[L], A = LA[L];
    constexpr int HW = S * S, M = 32 * HW, K = 9 * C, O = 95 * A;
    constexpr int ROWOFF = LROW[L], A4 = 4 * A;

    __shared__ short As[128 * 32];
    __shared__ short Bs[128 * 32];

    const int t    = threadIdx.x;
    const int m0   = blockIdx.x * 128;
    const int n0   = blockIdx.y * 128;
    const int lane = t & 63;
    const int wid  = t >> 6;
    const int lrow = lane >> 2;     // 0..15 row within 16-row load group
    const int kq   = lane & 3;      // 16B chunk within BK=32

    // per-lane A row addresses + per-tap validity masks (taps hit zero page when invalid)
    const short* abase[2]; unsigned vmask[2];
#pragma unroll
    for (int j = 0; j < 2; ++j) {
        int m = m0 + wid * 32 + j * 16 + lrow;
        int mm = m < M ? m : (M - 1);
        int n = mm / HW;
        int rem = mm - n * HW;
        int y = rem / S, x = rem - (rem / S) * S;
        abase[j] = ft + ((size_t)n * HW + rem) * C + kq * 8;
        unsigned msk = 0;
#pragma unroll
        for (int r = 0; r < 9; ++r) {
            int dy = r / 3 - 1, dx = r % 3 - 1;
            if ((unsigned)(y + dy) < (unsigned)S && (unsigned)(x + dx) < (unsigned)S)
                msk |= 1u << r;
        }
        vmask[j] = msk;
    }
    // per-lane B row addresses (clamped; stores masked in epilogue)
    const short* bbase[2];
#pragma unroll
    for (int j = 0; j < 2; ++j) {
        int o = n0 + wid * 32 + j * 16 + lrow;
        if (o >= O) o = O - 1;
        bbase[j] = wc + (size_t)o * K + kq * 8;
    }
    const short* zbl = zb + kq * 8;

    // wave-uniform LDS destinations (bytes handled via element indexing; rows of 32 shorts)
    short* const ldsA0 = &As[(wid * 32) * 32];
    short* const ldsA1 = &As[(wid * 32 + 16) * 32];
    short* const ldsB0 = &Bs[(wid * 32) * 32];
    short* const ldsB1 = &Bs[(wid * 32 + 16) * 32];

    const int wm    = (wid & 1) * 64;
    const int wn    = (wid >> 1) * 64;
    const int lcol  = lane & 15;
    const int lquad = lane >> 4;

    floatx4 acc[4][4];
#pragma unroll
    for (int i = 0; i < 4; ++i)
#pragma unroll
        for (int j = 0; j < 4; ++j)
#pragma unroll
            for (int q = 0; q < 4; ++q) acc[i][j][q] = 0.f;

#pragma unroll 1
    for (int r = 0; r < 9; ++r) {
        // tap offset in elements (can be negative); compile-time per r
        const int dy = r / 3 - 1, dx = r % 3 - 1;
        const int roff = (dy * S + dx) * C;
        const short* pa0 = ((vmask[0] >> r) & 1) ? abase[0] + roff : zbl;
        const short* pa1 = ((vmask[1] >> r) & 1) ? abase[1] + roff : zbl;
        const short* pb0 = bbase[0] + r * C;
        const short* pb1 = bbase[1] + r * C;
#pragma unroll 1
        for (int c0 = 0; c0 < C; c0 += 32) {
            __syncthreads();                         // prior MFMA reads done before overwrite
            GLL(pa0 + c0, ldsA0);
            GLL(pa1 + c0, ldsA1);
            GLL(pb0 + c0, ldsB0);
            GLL(pb1 + c0, ldsB1);
            __syncthreads();                         // vmcnt drained -> LDS visible
            short8 af[4], bfr[4];
#pragma unroll
            for (int f = 0; f < 4; ++f) {
                af[f]  = *(const short8*)&As[(wm + f * 16 + lcol) * 32 + lquad * 8];
                bfr[f] = *(const short8*)&Bs[(wn + f * 16 + lcol) * 32 + lquad * 8];
            }
#pragma unroll
            for (int i = 0; i < 4; ++i)
#pragma unroll
                for (int j = 0; j < 4; ++j)
                    acc[i][j] = __builtin_amdgcn_mfma_f32_16x16x32_bf16(af[i], bfr[j], acc[i][j], 0, 0, 0);
        }
    }

    // ---------------- epilogue: scatter into [n, 8732, {4|91}] ----------------
    float* const bbox = out;
    float* const cls  = out + CLSOFF;
    int rn[16], rbase[16]; bool rv[16];
#pragma unroll
    for (int fm = 0; fm < 4; ++fm)
#pragma unroll
        for (int rg = 0; rg < 4; ++rg) {
            int idx = fm * 4 + rg;
            int mr = m0 + wm + fm * 16 + lquad * 4 + rg;
            rv[idx] = mr < M;
            int mm = rv[idx] ? mr : 0;
            int n = mm / HW;
            int rem = mm - n * HW;
            rn[idx] = n;
            rbase[idx] = ROWOFF + rem * A;
        }
#pragma unroll 1
    for (int fn = 0; fn < 4; ++fn) {
        int o = n0 + wn + fn * 16 + lcol;
        if (o >= O) continue;
        if (o < A4) {
            int a = o >> 2, cc = o & 3;
            float bias = reg_b[o];
#pragma unroll
            for (int fm = 0; fm < 4; ++fm)
#pragma unroll
                for (int rg = 0; rg < 4; ++rg) {
                    int idx = fm * 4 + rg;
                    if (!rv[idx]) continue;
                    bbox[((size_t)rn[idx] * 8732 + rbase[idx] + a) * 4 + cc] = acc[fm][fn][rg] + bias;
                }
        } else {
            int oc = o - A4;
            int a = oc / 91, cc = oc - a * 91;
            float bias = cls_b[oc];
#pragma unroll
            for (int fm = 0; fm < 4; ++fm)
#pragma unroll
                for (int rg = 0; rg < 4; ++rg) {
                    int idx = fm * 4 + rg;
                    if (!rv[idx]) continue;
                    cls[((size_t)rn[idx] * 8732 + rbase[idx] + a) * 91 + cc] = acc[fm][fn][rg] + bias;
                }
        }
    }
}

// ---------------- naive fallback (only if ws too small) ----------------
template<int L>
__global__ void naive_conv(const float* __restrict__ feat,
                           const float* __restrict__ cw, const float* __restrict__ cb,
                           const float* __restrict__ rw, const float* __restrict__ rb,
                           float* __restrict__ out)
{
    constexpr int C = LC[L], S = LS[L], A = LA[L];
    constexpr int HW = S * S, M = 32 * HW, A4 = 4 * A, ROWOFF = LROW[L];
    int m = blockIdx.x * 256 + threadIdx.x;
    if (m >= M) return;
    int o = blockIdx.y;
    int n = m / HW, rem = m - n * HW, h = rem / S, w = rem - (rem / S) * S;
    bool isreg = o < A4;
    const float* wr = isreg ? (rw + (size_t)o * C * 9) : (cw + (size_t)(o - A4) * C * 9);
    float sum = isreg ? rb[o] : cb[o - A4];
    const float* fb = feat + (size_t)n * C * HW;
    for (int c = 0; c < C; ++c) {
#pragma unroll
        for (int r = 0; r < 9; ++r) {
            int y = h + r / 3 - 1, x = w + r % 3 - 1;
            if ((unsigned)y < (unsigned)S && (unsigned)x < (unsigned)S)
                sum += wr[c * 9 + r] * fb[(size_t)c * HW + y * S + x];
        }
    }
    int rowidx = ROWOFF + rem * A;
    if (isreg) out[((size_t)n * 8732 + rowidx + (o >> 2)) * 4 + (o & 3)] = sum;
    else {
        int oc = o - A4;
        int a = oc / 91;
        (out + CLSOFF)[((size_t)n * 8732 + rowidx + a) * 91 + (oc - a * 91)] = sum;
    }
}

// ---------------- host ----------------
extern "C" void kernel_launch(void* const* d_in, const int* in_sizes, int n_in,
                              void* d_out, int out_size, void* d_ws, size_t ws_size,
                              hipStream_t stream)
{
    const float *feat[6], *cw[6], *cb[6], *rw[6], *rb[6];
    for (int i = 0; i < 6; ++i) {
        feat[i] = (const float*)d_in[5 * i + 0];
        cw[i]   = (const float*)d_in[5 * i + 1];
        cb[i]   = (const float*)d_in[5 * i + 2];
        rw[i]   = (const float*)d_in[5 * i + 3];
        rb[i]   = (const float*)d_in[5 * i + 4];
    }
    float* out = (float*)d_out;

    if (ws_size >= WS_NEEDED) {
        short* ws  = (short*)d_ws;
        short* wcp = ws + WCBASE;
        short* zb  = ws + ZOFF;
        transpose_feat<0><<<dim3(23, 8, 32), 256, 0, stream>>>(feat[0], ws + FOFF[0]);
        transpose_feat<1><<<dim3(6, 16, 32), 256, 0, stream>>>(feat[1], ws + FOFF[1]);
        transpose_feat<2><<<dim3(2, 8, 32), 256, 0, stream>>>(feat[2], ws + FOFF[2]);
        transpose_feat<3><<<dim3(1, 4, 32), 256, 0, stream>>>(feat[3], ws + FOFF[3]);
        transpose_feat<4><<<dim3(1, 4, 32), 256, 0, stream>>>(feat[4], ws + FOFF[4]);
        transpose_feat<5><<<dim3(1, 4, 32), 256, 0, stream>>>(feat[5], ws + FOFF[5]);
        WPtrs wp;
        for (int i = 0; i < 6; ++i) { wp.cw[i] = cw[i]; wp.rw[i] = rw[i]; }
        reorder_weights<<<6200, 256, 0, stream>>>(wp, wcp, zb);
        gemm_level<0><<<dim3(361, 3), 256, 0, stream>>>(ws + FOFF[0], wcp + WOFF[0], zb, cb[0], rb[0], out);
        gemm_level<1><<<dim3(91, 5),  256, 0, stream>>>(ws + FOFF[1], wcp + WOFF[1], zb, cb[1], rb[1], out);
        gemm_level<2><<<dim3(25, 5),  256, 0, stream>>>(ws + FOFF[2], wcp + WOFF[2], zb, cb[2], rb[2], out);
        gemm_level<3><<<dim3(7, 5),   256, 0, stream>>>(ws + FOFF[3], wcp + WOFF[3], zb, cb[3], rb[3], out);
        gemm_level<4><<<dim3(3, 3),   256, 0, stream>>>(ws + FOFF[4], wcp + WOFF[4], zb, cb[4], rb[4], out);
        gemm_level<5><<<dim3(1, 3),   256, 0, stream>>>(ws + FOFF[5], wcp + WOFF[5], zb, cb[5], rb[5], out);
    } else {
        naive_conv<0><<<dim3(181, 380), 256, 0, stream>>>(feat[0], cw[0], cb[0], rw[0], rb[0], out);
        naive_conv<1><<<dim3(46, 570),  256, 0, stream>>>(feat[1], cw[1], cb[1], rw[1], rb[1], out);
        naive_conv<2><<<dim3(13, 570),  256, 0, stream>>>(feat[2], cw[2], cb[2], rw[2], rb[2], out);
        naive_conv<3><<<dim3(4, 570),   256, 0, stream>>>(feat[3], cw[3], cb[3], rw[3], rb[3], out);
        naive_conv<4><<<dim3(2, 380),   256, 0, stream>>>(feat[4], cw[4], cb[4], rw[4], rb[4], out);
        naive_conv<5><<<dim3(1, 380),   256, 0, stream>>>(feat[5], cw[5], cb[5], rw[5], rb[5], out);
    }
}

// Round 3
// 1138.636 us; speedup vs baseline: 4.1127x; 4.0528x over previous
//
#include <hip/hip_runtime.h>

typedef __attribute__((ext_vector_type(8))) short short8;
typedef __attribute__((ext_vector_type(4))) float floatx4;

#define DEVI __device__ __forceinline__

// direct global->LDS, 16B per lane; LDS dest = wave-uniform base + lane*16
#define GLL(g, l) __builtin_amdgcn_global_load_lds(                      \
    (const __attribute__((address_space(1))) void*)(g),                  \
    (__attribute__((address_space(3))) void*)(l), 16, 0, 0)

// ---------------- level constants ----------------
constexpr int LC[6]   = {512, 1024, 512, 256, 256, 256};   // in channels
constexpr int LS[6]   = {38, 19, 10, 5, 3, 1};             // spatial
constexpr int LA[6]   = {4, 6, 6, 6, 4, 4};                // anchors
constexpr int LROW[6] = {0, 5776, 7942, 8542, 8692, 8728}; // row offsets into 8732
constexpr long FOFF[6] = {0, 23658496, 35487744, 37126144, 37330944, 37404672}; // featT elem offsets
constexpr long WCBASE  = 37412864;                                              // Wc elem base
constexpr long WOFF[6] = {0, 1751040, 7004160, 9630720, 10944000, 11819520};    // Wc per-level offsets
constexpr int  GOFF[7] = {0, 218880, 875520, 1203840, 1368000, 1477440, 1586880}; // groups of 8
constexpr long ZOFF    = 50107904;   // zero-sentinel page (elems)
constexpr int  ZSIZE   = 1088;
constexpr long CLSOFF  = 1117696;    // 32*8732*4
constexpr size_t WS_NEEDED = (size_t)(ZOFF + ZSIZE) * 2;

DEVI short f2bf(float f) {
    union { float f; unsigned u; } x; x.f = f;
    unsigned u = x.u + 0x7fffu + ((x.u >> 16) & 1u);   // RNE
    return (short)(u >> 16);
}

// ---------------- transpose feat [n,c,pix] f32 -> [n,pix,c] bf16 ----------------
template<int L>
__global__ void transpose_feat(const float* __restrict__ feat, short* __restrict__ ft) {
    constexpr int C = LC[L], S = LS[L], HW = S * S;
    const int n  = blockIdx.z;
    const int p0 = blockIdx.x * 64;
    const int c0 = blockIdx.y * 64;
    __shared__ float tile[64][65];
    const int t = threadIdx.x;
    const float* fb = feat + ((size_t)n * C + c0) * HW;
#pragma unroll
    for (int e = 0; e < 16; ++e) {
        int idx = e * 256 + t;
        int p = idx & 63, cc = idx >> 6;
        int pix = p0 + p;
        tile[cc][p] = (pix < HW) ? fb[(size_t)cc * HW + pix] : 0.f;
    }
    __syncthreads();
    short* ob = ft + ((size_t)n * HW) * C + c0;
#pragma unroll
    for (int e = 0; e < 16; ++e) {
        int idx = e * 256 + t;
        int cc = idx & 63, p = idx >> 6;
        int pix = p0 + p;
        if (pix < HW) ob[(size_t)pix * C + cc] = f2bf(tile[cc][p]);
    }
}

// ---------------- reorder weights: combined [o][k=r*C+c] bf16; also zero-fill sentinel ----------------
struct WPtrs { const float* cw[6]; const float* rw[6]; };

__global__ void reorder_weights(WPtrs p, short* __restrict__ wc, short* __restrict__ zb) {
    int g = blockIdx.x * 256 + threadIdx.x;
    if (g >= GOFF[6]) {
        if (blockIdx.x == 6199 && threadIdx.x < ZSIZE / 8) {
            short8 z;
#pragma unroll
            for (int q = 0; q < 8; ++q) z[q] = 0;
            *(short8*)(zb + threadIdx.x * 8) = z;
        }
        return;
    }
    int L = 0;
#pragma unroll
    for (int q = 1; q < 6; ++q) if (g >= GOFF[q]) L = q;
    int e = g - GOFF[L];
    const int C = LC[L], A = LA[L];
    const unsigned K8 = (unsigned)(9 * C) >> 3, C8 = (unsigned)C >> 3;
    unsigned o    = (unsigned)e / K8;
    unsigned remk = (unsigned)e - o * K8;
    unsigned r    = remk / C8;
    unsigned c    = (remk - r * C8) << 3;
    int A4 = A << 2;
    const float* src = ((int)o < A4) ? (p.rw[L] + (size_t)o * 9 * C)
                                     : (p.cw[L] + (size_t)(o - A4) * 9 * C);
    short8 v;
#pragma unroll
    for (int j = 0; j < 8; ++j) v[j] = f2bf(src[(size_t)(c + j) * 9 + r]);
    *(short8*)(wc + (size_t)WOFF[L] + (size_t)o * (9 * C) + (size_t)r * C + c) = v;
}

// ---------------- implicit-GEMM conv, m97 structure: global_load_lds, 128x128x32 ----------------
template<int L>
__global__ __launch_bounds__(256)
void gemm_level(const short* __restrict__ ft, const short* __restrict__ wc,
                const short* __restrict__ zb,
                const float* __restrict__ cls_b, const float* __restrict__ reg_b,
                float* __restrict__ out)
{
    constexpr int C = LC[L], S = LS[L], A = LA[L];
    constexpr int HW = S * S, M = 32 * HW, K = 9 * C, O = 95 * A;
    constexpr int ROWOFF = LROW[L], A4 = 4 * A;
    constexpr int NM = (M + 127) / 128, NB = (O + 127) / 128;
    constexpr int TOT = NM * NB, TPX = (TOT + 7) / 8;

    __shared__ short As[128 * 32];
    __shared__ short Bs[128 * 32];

    // XCD swizzle: consecutive tiles (by fastest) stay on one XCD for A/L2 reuse
    const int lb = blockIdx.x;
    const int tt = (lb & 7) * TPX + (lb >> 3);
    if (tt >= TOT) return;
    const int m0 = (tt / NB) * 128;
    const int n0 = (tt % NB) * 128;

    const int t    = threadIdx.x;
    const int lane = t & 63;
    const int wid  = t >> 6;
    const int lrow = lane >> 2;     // 0..15 row within 16-row load group
    const int kq   = lane & 3;      // 16B chunk within BK=32

    // per-lane A row addresses + per-tap validity masks (taps hit zero page when invalid)
    const short* abase[2]; unsigned vmask[2];
#pragma unroll
    for (int j = 0; j < 2; ++j) {
        int m = m0 + wid * 32 + j * 16 + lrow;
        int mm = m < M ? m : (M - 1);
        int n = mm / HW;
        int rem = mm - n * HW;
        int y = rem / S, x = rem - (rem / S) * S;
        abase[j] = ft + ((size_t)n * HW + rem) * C + kq * 8;
        unsigned msk = 0;
#pragma unroll
        for (int r = 0; r < 9; ++r) {
            int dy = r / 3 - 1, dx = r % 3 - 1;
            if ((unsigned)(y + dy) < (unsigned)S && (unsigned)(x + dx) < (unsigned)S)
                msk |= 1u << r;
        }
        vmask[j] = msk;
    }
    // per-lane B row addresses (clamped; stores masked in epilogue)
    const short* bbase[2];
#pragma unroll
    for (int j = 0; j < 2; ++j) {
        int o = n0 + wid * 32 + j * 16 + lrow;
        if (o >= O) o = O - 1;
        bbase[j] = wc + (size_t)o * K + kq * 8;
    }
    const short* zbl = zb + kq * 8;

    // wave-uniform LDS destinations (rows of 32 shorts = 64 B)
    short* const ldsA0 = &As[(wid * 32) * 32];
    short* const ldsA1 = &As[(wid * 32 + 16) * 32];
    short* const ldsB0 = &Bs[(wid * 32) * 32];
    short* const ldsB1 = &Bs[(wid * 32 + 16) * 32];

    const int wm    = (wid & 1) * 64;
    const int wn    = (wid >> 1) * 64;
    const int lcol  = lane & 15;
    const int lquad = lane >> 4;

    floatx4 acc[4][4];
#pragma unroll
    for (int i = 0; i < 4; ++i)
#pragma unroll
        for (int j = 0; j < 4; ++j)
#pragma unroll
            for (int q = 0; q < 4; ++q) acc[i][j][q] = 0.f;

#pragma unroll 1
    for (int r = 0; r < 9; ++r) {
        const int dy = r / 3 - 1, dx = r % 3 - 1;
        const int roff = (dy * S + dx) * C;
        const short* pa0 = ((vmask[0] >> r) & 1) ? abase[0] + roff : zbl;
        const short* pa1 = ((vmask[1] >> r) & 1) ? abase[1] + roff : zbl;
        const short* pb0 = bbase[0] + r * C;
        const short* pb1 = bbase[1] + r * C;
#pragma unroll 1
        for (int c0 = 0; c0 < C; c0 += 32) {
            __syncthreads();                         // prior MFMA ds_reads done before overwrite
            GLL(pa0 + c0, ldsA0);
            GLL(pa1 + c0, ldsA1);
            GLL(pb0 + c0, ldsB0);
            GLL(pb1 + c0, ldsB1);
            __syncthreads();                         // vmcnt drained -> LDS visible
            short8 af[4], bfr[4];
#pragma unroll
            for (int f = 0; f < 4; ++f) {
                af[f]  = *(const short8*)&As[(wm + f * 16 + lcol) * 32 + lquad * 8];
                bfr[f] = *(const short8*)&Bs[(wn + f * 16 + lcol) * 32 + lquad * 8];
            }
#pragma unroll
            for (int i = 0; i < 4; ++i)
#pragma unroll
                for (int j = 0; j < 4; ++j)
                    acc[i][j] = __builtin_amdgcn_mfma_f32_16x16x32_bf16(af[i], bfr[j], acc[i][j], 0, 0, 0);
        }
    }

    // ---------------- epilogue: FULLY UNROLLED (all acc indices compile-time!) ----------------
    // dynamic indexing into acc forces it into scratch -> 9 GB/dispatch spill traffic (round 1/2 bug)
    float* const bbox = out;
    float* const cls  = out + CLSOFF;
    int rn[16], rbase[16]; bool rv[16];
#pragma unroll
    for (int fm = 0; fm < 4; ++fm)
#pragma unroll
        for (int rg = 0; rg < 4; ++rg) {
            int idx = fm * 4 + rg;
            int mr = m0 + wm + fm * 16 + lquad * 4 + rg;
            rv[idx] = mr < M;
            int mm = rv[idx] ? mr : 0;
            int n = mm / HW;
            int rem = mm - n * HW;
            rn[idx] = n;
            rbase[idx] = ROWOFF + rem * A;
        }
#pragma unroll
    for (int fn = 0; fn < 4; ++fn) {
        int o = n0 + wn + fn * 16 + lcol;
        if (o < O) {
            if (o < A4) {
                int a = o >> 2, cc = o & 3;
                float bias = reg_b[o];
#pragma unroll
                for (int fm = 0; fm < 4; ++fm)
#pragma unroll
                    for (int rg = 0; rg < 4; ++rg) {
                        int idx = fm * 4 + rg;
                        if (rv[idx])
                            bbox[((size_t)rn[idx] * 8732 + rbase[idx] + a) * 4 + cc] = acc[fm][fn][rg] + bias;
                    }
            } else {
                int oc = o - A4;
                int a = oc / 91, cc = oc - a * 91;
                float bias = cls_b[oc];
#pragma unroll
                for (int fm = 0; fm < 4; ++fm)
#pragma unroll
                    for (int rg = 0; rg < 4; ++rg) {
                        int idx = fm * 4 + rg;
                        if (rv[idx])
                            cls[((size_t)rn[idx] * 8732 + rbase[idx] + a) * 91 + cc] = acc[fm][fn][rg] + bias;
                    }
            }
        }
    }
}

// ---------------- naive fallback (only if ws too small) ----------------
template<int L>
__global__ void naive_conv(const float* __restrict__ feat,
                           const float* __restrict__ cw, const float* __restrict__ cb,
                           const float* __restrict__ rw, const float* __restrict__ rb,
                           float* __restrict__ out)
{
    constexpr int C = LC[L], S = LS[L], A = LA[L];
    constexpr int HW = S * S, M = 32 * HW, A4 = 4 * A, ROWOFF = LROW[L];
    int m = blockIdx.x * 256 + threadIdx.x;
    if (m >= M) return;
    int o = blockIdx.y;
    int n = m / HW, rem = m - n * HW, h = rem / S, w = rem - (rem / S) * S;
    bool isreg = o < A4;
    const float* wr = isreg ? (rw + (size_t)o * C * 9) : (cw + (size_t)(o - A4) * C * 9);
    float sum = isreg ? rb[o] : cb[o - A4];
    const float* fb = feat + (size_t)n * C * HW;
    for (int c = 0; c < C; ++c) {
#pragma unroll
        for (int r = 0; r < 9; ++r) {
            int y = h + r / 3 - 1, x = w + r % 3 - 1;
            if ((unsigned)y < (unsigned)S && (unsigned)x < (unsigned)S)
                sum += wr[c * 9 + r] * fb[(size_t)c * HW + y * S + x];
        }
    }
    int rowidx = ROWOFF + rem * A;
    if (isreg) out[((size_t)n * 8732 + rowidx + (o >> 2)) * 4 + (o & 3)] = sum;
    else {
        int oc = o - A4;
        int a = oc / 91;
        (out + CLSOFF)[((size_t)n * 8732 + rowidx + a) * 91 + (oc - a * 91)] = sum;
    }
}

// ---------------- host ----------------
extern "C" void kernel_launch(void* const* d_in, const int* in_sizes, int n_in,
                              void* d_out, int out_size, void* d_ws, size_t ws_size,
                              hipStream_t stream)
{
    const float *feat[6], *cw[6], *cb[6], *rw[6], *rb[6];
    for (int i = 0; i < 6; ++i) {
        feat[i] = (const float*)d_in[5 * i + 0];
        cw[i]   = (const float*)d_in[5 * i + 1];
        cb[i]   = (const float*)d_in[5 * i + 2];
        rw[i]   = (const float*)d_in[5 * i + 3];
        rb[i]   = (const float*)d_in[5 * i + 4];
    }
    float* out = (float*)d_out;

    if (ws_size >= WS_NEEDED) {
        short* ws  = (short*)d_ws;
        short* wcp = ws + WCBASE;
        short* zb  = ws + ZOFF;
        transpose_feat<0><<<dim3(23, 8, 32), 256, 0, stream>>>(feat[0], ws + FOFF[0]);
        transpose_feat<1><<<dim3(6, 16, 32), 256, 0, stream>>>(feat[1], ws + FOFF[1]);
        transpose_feat<2><<<dim3(2, 8, 32), 256, 0, stream>>>(feat[2], ws + FOFF[2]);
        transpose_feat<3><<<dim3(1, 4, 32), 256, 0, stream>>>(feat[3], ws + FOFF[3]);
        transpose_feat<4><<<dim3(1, 4, 32), 256, 0, stream>>>(feat[4], ws + FOFF[4]);
        transpose_feat<5><<<dim3(1, 4, 32), 256, 0, stream>>>(feat[5], ws + FOFF[5]);
        WPtrs wp;
        for (int i = 0; i < 6; ++i) { wp.cw[i] = cw[i]; wp.rw[i] = rw[i]; }
        reorder_weights<<<6200, 256, 0, stream>>>(wp, wcp, zb);
        // grid = 8 * TPX per level (swizzle-padded): L0:1088 L1:456 L2:128 L3:40 L4:16 L5:8
        gemm_level<0><<<1088, 256, 0, stream>>>(ws + FOFF[0], wcp + WOFF[0], zb, cb[0], rb[0], out);
        gemm_level<1><<<456,  256, 0, stream>>>(ws + FOFF[1], wcp + WOFF[1], zb, cb[1], rb[1], out);
        gemm_level<2><<<128,  256, 0, stream>>>(ws + FOFF[2], wcp + WOFF[2], zb, cb[2], rb[2], out);
        gemm_level<3><<<40,   256, 0, stream>>>(ws + FOFF[3], wcp + WOFF[3], zb, cb[3], rb[3], out);
        gemm_level<4><<<16,   256, 0, stream>>>(ws + FOFF[4], wcp + WOFF[4], zb, cb[4], rb[4], out);
        gemm_level<5><<<8,    256, 0, stream>>>(ws + FOFF[5], wcp + WOFF[5], zb, cb[5], rb[5], out);
    } else {
        naive_conv<0><<<dim3(181, 380), 256, 0, stream>>>(feat[0], cw[0], cb[0], rw[0], rb[0], out);
        naive_conv<1><<<dim3(46, 570),  256, 0, stream>>>(feat[1], cw[1], cb[1], rw[1], rb[1], out);
        naive_conv<2><<<dim3(13, 570),  256, 0, stream>>>(feat[2], cw[2], cb[2], rw[2], rb[2], out);
        naive_conv<3><<<dim3(4, 570),   256, 0, stream>>>(feat[3], cw[3], cb[3], rw[3], rb[3], out);
        naive_conv<4><<<dim3(2, 380),   256, 0, stream>>>(feat[4], cw[4], cb[4], rw[4], rb[4], out);
        naive_conv<5><<<dim3(1, 380),   256, 0, stream>>>(feat[5], cw[5], cb[5], rw[5], rb[5], out);
    }
}